// Round 6
// baseline (330.774 us; speedup 1.0000x reference)
//
#include <hip/hip_runtime.h>
#include <hip/hip_cooperative_groups.h>
#include <cfloat>
#include <cmath>

namespace cg = cooperative_groups;

#define NPTS 131072
#define NC   512
#define NREP 4
#define NT   (NPTS / 128)

// ws float-index layout:
//  PM4  [0, 2048)      : per-component float4 (2*mu/2s2, w - |mu|^2/2s2)
//  PQ4  [2048, 4096)   : per-component float4 (mu_new[3], A_c)
//  ST4  [4096, 12288)  : NREP replicas x 512 comps x float4 (Tx,Ty,Tz,S)
//  MISC [12288, 12296) : [0]=sum|x|^2, [1]=inv2s2_new (fallback only), [3]=sum(gamma*lgamma)
// z_n staged in d_out[3n] (E phase writes, final phase reads then overwrites).
#define PM4_OFF  0
#define PQ4_OFF  2048
#define ST4_OFF  4096
#define MISC_OFF 12288

__device__ __forceinline__ float waveSum(float v) {
#pragma unroll
  for (int off = 32; off > 0; off >>= 1) v += __shfl_down(v, off, 64);
  return v;
}
__device__ __forceinline__ float waveMax(float v) {
#pragma unroll
  for (int off = 32; off > 0; off >>= 1) v = fmaxf(v, __shfl_down(v, off, 64));
  return v;
}

// ===========================================================================
// Fused cooperative kernel: prologue(pm) -> E tiles -> grid.sync ->
// redundant M-step -> final tiles. Round-0 code for E/final (the only
// structure measured at 75% VALUBusy); fusion removes ~3 launch gaps.
// ===========================================================================
__global__ __launch_bounds__(512, 8) void k_em(
    const float* __restrict__ X, const float* __restrict__ mu,
    const float* __restrict__ w, const float* __restrict__ sigma,
    float4* __restrict__ pm, float4* __restrict__ pq,
    float* __restrict__ ST, float* __restrict__ misc,
    float* __restrict__ out) {
  __shared__ float4 s_pt[128];     // (x0,x1,x2,z)
  __shared__ float2 s_ms[4][128];  // per-chunk (max, sumexp)
  __shared__ float4 s_y[4][128];
  __shared__ float  s_red[8];
  __shared__ float  s_red2[8];
  __shared__ float  s_bc[4];

  const int t = threadIdx.x;
  const int p = t & 127;
  const int ch = __builtin_amdgcn_readfirstlane(t >> 7);  // wave-uniform
  const int nblk = gridDim.x;

  // --- prologue: every block writes IDENTICAL pm (benign duplicate race;
  //     each block reads its own writes, so no cross-block ordering needed) ---
  {
    const float sg = sigma[0];
    const float inv2s2 = 1.0f / (2.0f * sg * sg);
    const float m0 = mu[3 * t], m1 = mu[3 * t + 1], m2 = mu[3 * t + 2];
    pm[t] = make_float4(2.0f * inv2s2 * m0, 2.0f * inv2s2 * m1,
                        2.0f * inv2s2 * m2,
                        w[t] - (m0 * m0 + m1 * m1 + m2 * m2) * inv2s2);
  }
  __syncthreads();

  // --- E phase: round-0 k_estep body, grid-strided over tiles ---
  for (int tile = blockIdx.x; tile < NT; tile += nblk) {
    const int n = tile * 128 + p;
    const float x0 = X[3 * n], x1 = X[3 * n + 1], x2 = X[3 * n + 2];

    const float4* __restrict__ pmc = pm + ch * 128;
    float ma = -FLT_MAX, mb = -FLT_MAX, mc = -FLT_MAX, md = -FLT_MAX;
#pragma unroll 4
    for (int i = 0; i < 128; i += 4) {
      float4 a = pmc[i], b = pmc[i + 1], c = pmc[i + 2], d = pmc[i + 3];
      ma = fmaxf(ma, fmaf(a.x, x0, fmaf(a.y, x1, fmaf(a.z, x2, a.w))));
      mb = fmaxf(mb, fmaf(b.x, x0, fmaf(b.y, x1, fmaf(b.z, x2, b.w))));
      mc = fmaxf(mc, fmaf(c.x, x0, fmaf(c.y, x1, fmaf(c.z, x2, c.w))));
      md = fmaxf(md, fmaf(d.x, x0, fmaf(d.y, x1, fmaf(d.z, x2, d.w))));
    }
    const float m = fmaxf(fmaxf(ma, mb), fmaxf(mc, md));
    float sa = 0.f, sb = 0.f, sc = 0.f, sd = 0.f;
#pragma unroll 4
    for (int i = 0; i < 128; i += 4) {
      float4 a = pmc[i], b = pmc[i + 1], c = pmc[i + 2], d = pmc[i + 3];
      sa += __expf(fmaf(a.x, x0, fmaf(a.y, x1, fmaf(a.z, x2, a.w))) - m);
      sb += __expf(fmaf(b.x, x0, fmaf(b.y, x1, fmaf(b.z, x2, b.w))) - m);
      sc += __expf(fmaf(c.x, x0, fmaf(c.y, x1, fmaf(c.z, x2, c.w))) - m);
      sd += __expf(fmaf(d.x, x0, fmaf(d.y, x1, fmaf(d.z, x2, d.w))) - m);
    }
    s_ms[ch][p] = make_float2(m, (sa + sb) + (sc + sd));
    __syncthreads();

    if (t < 128) {  // thread t owns point p == t here
      float2 q0 = s_ms[0][t], q1 = s_ms[1][t], q2 = s_ms[2][t], q3 = s_ms[3][t];
      float M = fmaxf(fmaxf(q0.x, q1.x), fmaxf(q2.x, q3.x));
      float SS = q0.y * __expf(q0.x - M) + q1.y * __expf(q1.x - M) +
                 q2.y * __expf(q2.x - M) + q3.y * __expf(q3.x - M);
      float z = M + __logf(SS);
      s_pt[t] = make_float4(x0, x1, x2, z);
      out[3 * n] = z;  // staged for final phase (same block re-reads it)
    }
    __syncthreads();

    // phase C: thread t owns comp t across the tile's 128 points
    const float4 pc = pm[t];
    float Sg = 0.f, Tx = 0.f, Ty = 0.f, Tz = 0.f, La = 0.f;
#pragma unroll 4
    for (int i = 0; i < 128; ++i) {
      float4 pt = s_pt[i];  // broadcast read
      float l = fmaf(pc.x, pt.x, fmaf(pc.y, pt.y, fmaf(pc.z, pt.z, pc.w)));
      float d = l - pt.w;   // lgamma
      float g = __expf(d);
      Sg += g;
      Tx = fmaf(g, pt.x, Tx);
      Ty = fmaf(g, pt.y, Ty);
      Tz = fmaf(g, pt.z, Tz);
      La = fmaf(g, d, La);  // sum gamma * lgamma
    }
    float* st = ST + (((tile & (NREP - 1)) * 512 + t) << 2);
    atomicAdd(st + 0, Tx);
    atomicAdd(st + 1, Ty);
    atomicAdd(st + 2, Tz);
    atomicAdd(st + 3, Sg);

    float xx = (t < 128) ? (x0 * x0 + x1 * x1 + x2 * x2) : 0.f;
    float rx = waveSum(xx);
    float rl = waveSum(La);
    if ((t & 63) == 0) { s_red[t >> 6] = rx; s_red2[t >> 6] = rl; }
    __syncthreads();
    if (t == 0) {
      float vx = 0.f, vl = 0.f;
#pragma unroll
      for (int i = 0; i < 8; ++i) { vx += s_red[i]; vl += s_red2[i]; }
      atomicAdd(&misc[0], vx);
      atomicAdd(&misc[3], vl);
    }
  }

  __threadfence();        // release ST/misc/out(z) at device scope
  cg::this_grid().sync(); // all E-phase accumulations complete

  // --- M phase: every block computes mstep redundantly (identical result).
  //     pq duplicate-writes are benign; inv2s2n broadcast via s_bc[2]. ---
  {
    const float4* __restrict__ ST4 = (const float4*)ST;
    float Tx = 0.f, Ty = 0.f, Tz = 0.f, S = 0.f;
#pragma unroll
    for (int r = 0; r < NREP; ++r) {
      float4 v = ST4[r * 512 + t];
      Tx += v.x; Ty += v.y; Tz += v.z; S += v.w;
    }
    const float Sc = fmaxf(S, 1e-30f);
    const float h = __logf(Sc);
    const float m0 = Tx / Sc, m1 = Ty / Sc, m2 = Tz / Sc;

    const float o0 = mu[3 * t], o1 = mu[3 * t + 1], o2 = mu[3 * t + 2];
    const float gdp = S * (o0 * o0 + o1 * o1 + o2 * o2)
                      - 2.0f * (o0 * Tx + o1 * Ty + o2 * Tz);

    float hm = waveMax(h);
    if ((t & 63) == 0) s_red[t >> 6] = hm;
    __syncthreads();
    if (t == 0) {
      float v = s_red[0];
      for (int i = 1; i < 8; ++i) v = fmaxf(v, s_red[i]);
      s_bc[0] = v;
    }
    __syncthreads();
    const float hM = s_bc[0];

    float es = waveSum(__expf(h - hM));
    float gs = waveSum(gdp);
    if ((t & 63) == 0) { s_red[t >> 6] = es; s_red2[t >> 6] = gs; }
    __syncthreads();
    if (t == 0) {
      float esum = 0.f, gsum = 0.f;
      for (int i = 0; i < 8; ++i) { esum += s_red[i]; gsum += s_red2[i]; }
      s_bc[1] = hM + __logf(esum);                           // lse(h)
      const float gd = fmaxf(misc[0] + gsum, 1e-20f);
      const float sn2 = gd * (1.0f / (3.0f * (float)NPTS));  // sigma_new^2
      s_bc[2] = 1.0f / (2.0f * sn2);                         // inv2s2_new
      s_bc[3] = 1.5f * __logf(sn2);                          // d*log(sigma_new)
    }
    __syncthreads();

    const float inv2s2n = s_bc[2];
    const float logpi = h - s_bc[1];
    const float A = (m0 * m0 + m1 * m1 + m2 * m2) * inv2s2n - logpi;
    pq[t] = make_float4(m0, m1, m2, A);  // identical duplicate writes

    float ca = waveSum(S * A);
    if ((t & 63) == 0) s_red[t >> 6] = ca;
    __syncthreads();
    if (t == 0 && blockIdx.x == 0) {  // Cfe seed, exactly once (out pre-zeroed)
      float v = 0.f;
      for (int i = 0; i < 8; ++i) v += s_red[i];
      atomicAdd(&out[NPTS * 3], v + misc[3] + (float)NPTS * s_bc[3]);
    }
  }
  __syncthreads();
  const float inv2s2n = s_bc[2];

  // --- final phase: round-0 k_final_dense body over the SAME owned tiles ---
  for (int tile = blockIdx.x; tile < NT; tile += nblk) {
    const int n = tile * 128 + p;
    const float x0 = X[3 * n], x1 = X[3 * n + 1], x2 = X[3 * n + 2];
    const float z = out[3 * n];  // staged by this block's E phase

    const float4* __restrict__ pmc = pm + ch * 128;
    const float4* __restrict__ pqc = pq + ch * 128;
    float y0 = 0.f, y1 = 0.f, y2 = 0.f;
#pragma unroll 4
    for (int i = 0; i < 128; ++i) {
      float4 pp = pmc[i];
      float4 qq = pqc[i];
      const float l = fmaf(pp.x, x0, fmaf(pp.y, x1, fmaf(pp.z, x2, pp.w))) - z;
      const float g = __expf(l);
      y0 = fmaf(g, qq.x, y0);
      y1 = fmaf(g, qq.y, y1);
      y2 = fmaf(g, qq.z, y2);
    }
    s_y[ch][p] = make_float4(y0, y1, y2, 0.f);
    __syncthreads();

    float cfe = 0.f;
    if (t < 128) {
      float4 a0 = s_y[0][t], a1 = s_y[1][t], a2 = s_y[2][t], a3 = s_y[3][t];
      const float Y0 = (a0.x + a1.x) + (a2.x + a3.x);
      const float Y1 = (a0.y + a1.y) + (a2.y + a3.y);
      const float Y2 = (a0.z + a1.z) + (a2.z + a3.z);
      cfe = -(Y0 * Y0 + Y1 * Y1 + Y2 * Y2) * inv2s2n;
      out[3 * n] = Y0;
      out[3 * n + 1] = Y1;
      out[3 * n + 2] = Y2;
    }
    float r = waveSum(cfe);
    if ((t & 63) == 0) s_red[t >> 6] = r;
    __syncthreads();
    if (t == 0) {
      float v = 0.f;
#pragma unroll
      for (int i = 0; i < 8; ++i) v += s_red[i];
      atomicAdd(&out[NPTS * 3], v);
    }
  }
}

// ===========================================================================
// Fallback path (round-0 proven kernels) if cooperative launch unavailable.
// ===========================================================================
__global__ __launch_bounds__(512) void k_prep(
    const float* __restrict__ mu, const float* __restrict__ w,
    const float* __restrict__ sigma, float4* __restrict__ pm,
    float* __restrict__ ST, float* __restrict__ misc) {
  const int t = threadIdx.x;
  const float sg = sigma[0];
  const float inv2s2 = 1.0f / (2.0f * sg * sg);
  const float m0 = mu[3 * t], m1 = mu[3 * t + 1], m2 = mu[3 * t + 2];
  pm[t] = make_float4(2.0f * inv2s2 * m0, 2.0f * inv2s2 * m1, 2.0f * inv2s2 * m2,
                      w[t] - (m0 * m0 + m1 * m1 + m2 * m2) * inv2s2);
#pragma unroll
  for (int r = 0; r < NREP * 4; ++r) ST[r * 512 + t] = 0.f;
  if (t < 8) misc[t] = 0.f;
}

__global__ __launch_bounds__(512, 8) void k_estep_fb(
    const float* __restrict__ X, const float4* __restrict__ pm,
    float* __restrict__ ST, float* __restrict__ misc,
    float* __restrict__ out) {
  __shared__ float4 s_pt[128];
  __shared__ float2 s_ms[4][128];
  __shared__ float  s_red[8];
  __shared__ float  s_red2[8];

  const int t = threadIdx.x;
  const int p = t & 127;
  const int ch = __builtin_amdgcn_readfirstlane(t >> 7);
  const int n = blockIdx.x * 128 + p;
  const float x0 = X[3 * n], x1 = X[3 * n + 1], x2 = X[3 * n + 2];

  const float4* __restrict__ pmc = pm + ch * 128;
  float ma = -FLT_MAX, mb = -FLT_MAX, mc = -FLT_MAX, md = -FLT_MAX;
#pragma unroll 4
  for (int i = 0; i < 128; i += 4) {
    float4 a = pmc[i], b = pmc[i + 1], c = pmc[i + 2], d = pmc[i + 3];
    ma = fmaxf(ma, fmaf(a.x, x0, fmaf(a.y, x1, fmaf(a.z, x2, a.w))));
    mb = fmaxf(mb, fmaf(b.x, x0, fmaf(b.y, x1, fmaf(b.z, x2, b.w))));
    mc = fmaxf(mc, fmaf(c.x, x0, fmaf(c.y, x1, fmaf(c.z, x2, c.w))));
    md = fmaxf(md, fmaf(d.x, x0, fmaf(d.y, x1, fmaf(d.z, x2, d.w))));
  }
  const float m = fmaxf(fmaxf(ma, mb), fmaxf(mc, md));
  float sa = 0.f, sb = 0.f, sc = 0.f, sd = 0.f;
#pragma unroll 4
  for (int i = 0; i < 128; i += 4) {
    float4 a = pmc[i], b = pmc[i + 1], c = pmc[i + 2], d = pmc[i + 3];
    sa += __expf(fmaf(a.x, x0, fmaf(a.y, x1, fmaf(a.z, x2, a.w))) - m);
    sb += __expf(fmaf(b.x, x0, fmaf(b.y, x1, fmaf(b.z, x2, b.w))) - m);
    sc += __expf(fmaf(c.x, x0, fmaf(c.y, x1, fmaf(c.z, x2, c.w))) - m);
    sd += __expf(fmaf(d.x, x0, fmaf(d.y, x1, fmaf(d.z, x2, d.w))) - m);
  }
  s_ms[ch][p] = make_float2(m, (sa + sb) + (sc + sd));
  __syncthreads();

  if (t < 128) {
    float2 q0 = s_ms[0][t], q1 = s_ms[1][t], q2 = s_ms[2][t], q3 = s_ms[3][t];
    float M = fmaxf(fmaxf(q0.x, q1.x), fmaxf(q2.x, q3.x));
    float SS = q0.y * __expf(q0.x - M) + q1.y * __expf(q1.x - M) +
               q2.y * __expf(q2.x - M) + q3.y * __expf(q3.x - M);
    float z = M + __logf(SS);
    s_pt[t] = make_float4(x0, x1, x2, z);
    out[3 * n] = z;
  }
  __syncthreads();

  const float4 pc = pm[t];
  float Sg = 0.f, Tx = 0.f, Ty = 0.f, Tz = 0.f, La = 0.f;
#pragma unroll 4
  for (int i = 0; i < 128; ++i) {
    float4 pt = s_pt[i];
    float l = fmaf(pc.x, pt.x, fmaf(pc.y, pt.y, fmaf(pc.z, pt.z, pc.w)));
    float d = l - pt.w;
    float g = __expf(d);
    Sg += g;
    Tx = fmaf(g, pt.x, Tx);
    Ty = fmaf(g, pt.y, Ty);
    Tz = fmaf(g, pt.z, Tz);
    La = fmaf(g, d, La);
  }
  float* st = ST + (((blockIdx.x & (NREP - 1)) * 512 + t) << 2);
  atomicAdd(st + 0, Tx);
  atomicAdd(st + 1, Ty);
  atomicAdd(st + 2, Tz);
  atomicAdd(st + 3, Sg);

  float xx = (t < 128) ? (x0 * x0 + x1 * x1 + x2 * x2) : 0.f;
  float rx = waveSum(xx);
  float rl = waveSum(La);
  if ((t & 63) == 0) { s_red[t >> 6] = rx; s_red2[t >> 6] = rl; }
  __syncthreads();
  if (t == 0) {
    float vx = 0.f, vl = 0.f;
#pragma unroll
    for (int i = 0; i < 8; ++i) { vx += s_red[i]; vl += s_red2[i]; }
    atomicAdd(&misc[0], vx);
    atomicAdd(&misc[3], vl);
  }
}

__global__ __launch_bounds__(512) void k_mstep_fb(
    const float* __restrict__ mu, const float4* __restrict__ ST4,
    float4* __restrict__ pq, float* __restrict__ misc,
    float* __restrict__ out) {
  __shared__ float s_red[8];
  __shared__ float s_red2[8];
  __shared__ float s_bc[4];
  const int t = threadIdx.x;

  float Tx = 0.f, Ty = 0.f, Tz = 0.f, S = 0.f;
#pragma unroll
  for (int r = 0; r < NREP; ++r) {
    float4 v = ST4[r * 512 + t];
    Tx += v.x; Ty += v.y; Tz += v.z; S += v.w;
  }
  const float Sc = fmaxf(S, 1e-30f);
  const float h = __logf(Sc);
  const float m0 = Tx / Sc, m1 = Ty / Sc, m2 = Tz / Sc;

  const float o0 = mu[3 * t], o1 = mu[3 * t + 1], o2 = mu[3 * t + 2];
  const float gdp = S * (o0 * o0 + o1 * o1 + o2 * o2)
                    - 2.0f * (o0 * Tx + o1 * Ty + o2 * Tz);

  float hm = waveMax(h);
  if ((t & 63) == 0) s_red[t >> 6] = hm;
  __syncthreads();
  if (t == 0) {
    float v = s_red[0];
    for (int i = 1; i < 8; ++i) v = fmaxf(v, s_red[i]);
    s_bc[0] = v;
  }
  __syncthreads();
  const float hM = s_bc[0];

  float es = waveSum(__expf(h - hM));
  float gs = waveSum(gdp);
  if ((t & 63) == 0) { s_red[t >> 6] = es; s_red2[t >> 6] = gs; }
  __syncthreads();
  if (t == 0) {
    float esum = 0.f, gsum = 0.f;
    for (int i = 0; i < 8; ++i) { esum += s_red[i]; gsum += s_red2[i]; }
    s_bc[1] = hM + __logf(esum);
    const float gd = fmaxf(misc[0] + gsum, 1e-20f);
    const float sn2 = gd * (1.0f / (3.0f * (float)NPTS));
    s_bc[2] = 1.0f / (2.0f * sn2);
    s_bc[3] = 1.5f * __logf(sn2);
  }
  __syncthreads();

  const float inv2s2n = s_bc[2];
  const float logpi = h - s_bc[1];
  const float A = (m0 * m0 + m1 * m1 + m2 * m2) * inv2s2n - logpi;
  pq[t] = make_float4(m0, m1, m2, A);

  float ca = waveSum(S * A);
  if ((t & 63) == 0) s_red[t >> 6] = ca;
  __syncthreads();
  if (t == 0) {
    float v = 0.f;
    for (int i = 0; i < 8; ++i) v += s_red[i];
    out[NPTS * 3] = v + misc[3] + (float)NPTS * s_bc[3];
    misc[1] = inv2s2n;
  }
}

__global__ __launch_bounds__(512, 8) void k_final_fb(
    const float* __restrict__ X, const float4* __restrict__ pm,
    const float4* __restrict__ pq, const float* __restrict__ misc,
    float* __restrict__ out) {
  __shared__ float4 s_y[4][128];
  __shared__ float  s_red[8];

  const int t = threadIdx.x;
  const int p = t & 127;
  const int ch = __builtin_amdgcn_readfirstlane(t >> 7);
  const int n = blockIdx.x * 128 + p;
  const float x0 = X[3 * n], x1 = X[3 * n + 1], x2 = X[3 * n + 2];
  const float z = out[3 * n];
  const float inv2s2n = misc[1];

  const float4* __restrict__ pmc = pm + ch * 128;
  const float4* __restrict__ pqc = pq + ch * 128;
  float y0 = 0.f, y1 = 0.f, y2 = 0.f;
#pragma unroll 4
  for (int i = 0; i < 128; ++i) {
    float4 pp = pmc[i];
    float4 qq = pqc[i];
    const float l = fmaf(pp.x, x0, fmaf(pp.y, x1, fmaf(pp.z, x2, pp.w))) - z;
    const float g = __expf(l);
    y0 = fmaf(g, qq.x, y0);
    y1 = fmaf(g, qq.y, y1);
    y2 = fmaf(g, qq.z, y2);
  }
  s_y[ch][p] = make_float4(y0, y1, y2, 0.f);
  __syncthreads();

  float cfe = 0.f;
  if (t < 128) {
    float4 a0 = s_y[0][t], a1 = s_y[1][t], a2 = s_y[2][t], a3 = s_y[3][t];
    const float Y0 = (a0.x + a1.x) + (a2.x + a3.x);
    const float Y1 = (a0.y + a1.y) + (a2.y + a3.y);
    const float Y2 = (a0.z + a1.z) + (a2.z + a3.z);
    cfe = -(Y0 * Y0 + Y1 * Y1 + Y2 * Y2) * inv2s2n;
    out[3 * n] = Y0;
    out[3 * n + 1] = Y1;
    out[3 * n + 2] = Y2;
  }
  float r = waveSum(cfe);
  if ((t & 63) == 0) s_red[t >> 6] = r;
  __syncthreads();
  if (t == 0) {
    float v = 0.f;
#pragma unroll
    for (int i = 0; i < 8; ++i) v += s_red[i];
    atomicAdd(&out[NPTS * 3], v);
  }
}

extern "C" void kernel_launch(void* const* d_in, const int* in_sizes, int n_in,
                              void* d_out, int out_size, void* d_ws, size_t ws_size,
                              hipStream_t stream) {
  const float* X = (const float*)d_in[0];
  const float* mu = (const float*)d_in[1];
  const float* w = (const float*)d_in[2];
  const float* sigma = (const float*)d_in[3];
  float* out = (float*)d_out;
  float* ws = (float*)d_ws;

  float4* pm = (float4*)(ws + PM4_OFF);
  float4* pq = (float4*)(ws + PQ4_OFF);
  float* ST = ws + ST4_OFF;
  float* misc = ws + MISC_OFF;

  // One-time capacity query (host-side, graph-capture-safe).
  static int s_grid = -1;
  if (s_grid < 0) {
    int dev = 0;
    hipGetDevice(&dev);
    int coop = 0;
    hipDeviceGetAttribute(&coop, hipDeviceAttributeCooperativeLaunch, dev);
    long cap = 0;
    if (coop) {
      int nb = 0, ncu = 0;
      hipOccupancyMaxActiveBlocksPerMultiprocessor(&nb, k_em, 512, 0);
      hipDeviceGetAttribute(&ncu, hipDeviceAttributeMultiprocessorCount, dev);
      cap = (long)nb * (long)ncu;
    }
    s_grid = (cap >= 64) ? (int)(cap < (long)NT ? cap : (long)NT) : 0;
  }

  if (s_grid > 0) {
    // zero ST replicas + misc (contiguous) and the Cfe accumulator slot
    hipMemsetAsync(ST, 0, (size_t)(NREP * NC * 4 + 8) * sizeof(float), stream);
    hipMemsetAsync(out + (size_t)NPTS * 3, 0, sizeof(float), stream);
    void* args[] = {(void*)&X, (void*)&mu, (void*)&w, (void*)&sigma,
                    (void*)&pm, (void*)&pq, (void*)&ST, (void*)&misc,
                    (void*)&out};
    hipError_t rc = hipLaunchCooperativeKernel(k_em, dim3(s_grid), dim3(512),
                                               args, 0u, stream);
    if (rc == hipSuccess) return;
    s_grid = 0;  // don't retry the cooperative path
  }

  // fallback: proven 4-kernel round-0 chain
  k_prep<<<1, 512, 0, stream>>>(mu, w, sigma, pm, ST, misc);
  k_estep_fb<<<NT, 512, 0, stream>>>(X, pm, ST, misc, out);
  k_mstep_fb<<<1, 512, 0, stream>>>(mu, (const float4*)ST, pq, misc, out);
  k_final_fb<<<NT, 512, 0, stream>>>(X, pm, pq, misc, out);
}

// Round 7
// 151.169 us; speedup vs baseline: 2.1881x; 2.1881x over previous
//
#include <hip/hip_runtime.h>
#include <cfloat>
#include <cmath>

#define NPTS 131072
#define NC   512
#define NREP 4
#define NT   (NPTS / 128)
#define L2E  1.4426950408889634f
#define LN2  0.6931471805599453f

// ws float-index layout (pm/pq now live in LDS only):
//  ST4  [4096, 12288)  : NREP replicas x 512 comps x float4 (Tx,Ty,Tz,S)
//  MISC [12288, 12296) : [0]=sum|x|^2, [3]=sum(gamma*lgamma)
// z_n (BASE-2 units) staged in d_out[3n]; Cfe accumulates in d_out[NPTS*3]
// (zeroed by k_estep block 0 -- stream order guarantees it precedes k_final).
#define ST4_OFF  4096
#define MISC_OFF 12288

__device__ __forceinline__ float waveSum(float v) {
#pragma unroll
  for (int off = 32; off > 0; off >>= 1) v += __shfl_down(v, off, 64);
  return v;
}
__device__ __forceinline__ float waveMax(float v) {
#pragma unroll
  for (int off = 32; off > 0; off >>= 1) v = fmaxf(v, __shfl_down(v, off, 64));
  return v;
}

// Packed BASE-2 component params: l2 = dot(pm.xyz, x) + pm.w is log2-domain,
// so every exp is a bare v_exp_f32 (validated bit-compatible in rounds 2-4).
__device__ __forceinline__ float4 packComp(
    const float* __restrict__ mu, const float* __restrict__ w,
    const float* __restrict__ sigma, int t) {
  const float sg = sigma[0];
  const float k2 = L2E / (2.0f * sg * sg);  // log2e / (2 sigma^2)
  const float m0 = mu[3 * t], m1 = mu[3 * t + 1], m2 = mu[3 * t + 2];
  return make_float4(2.0f * k2 * m0, 2.0f * k2 * m1, 2.0f * k2 * m2,
                     w[t] * L2E - (m0 * m0 + m1 * m1 + m2 * m2) * k2);
}

// ---------------------------------------------------------------------------
// E-step (round-0 structure, pm in LDS, base-2).
// block = 512 thr = 128 points x 4 comp-chunks.
// Phase A: per-chunk (max, sumexp2) -> combine -> z2. Phase C: thread owns
// one comp over 128 points (LDS broadcast); ST replica atomics.
// ---------------------------------------------------------------------------
__global__ __launch_bounds__(512, 8) void k_estep(
    const float* __restrict__ X, const float* __restrict__ mu,
    const float* __restrict__ w, const float* __restrict__ sigma,
    float* __restrict__ ST, float* __restrict__ misc,
    float* __restrict__ out) {
  __shared__ float4 s_pm[NC];      // packed comp params (base-2)
  __shared__ float4 s_pt[128];     // (x0,x1,x2,z2)
  __shared__ float2 s_ms[4][128];  // per-chunk (max2, sumexp2)
  __shared__ float  s_red[8];
  __shared__ float  s_red2[8];

  const int t = threadIdx.x;
  const int p = t & 127;
  const int ch = __builtin_amdgcn_readfirstlane(t >> 7);  // wave-uniform
  const int n = blockIdx.x * 128 + p;

  s_pm[t] = packComp(mu, w, sigma, t);
  if (blockIdx.x == 0 && t == 0) out[(size_t)NPTS * 3] = 0.f;  // Cfe slot
  const float x0 = X[3 * n], x1 = X[3 * n + 1], x2 = X[3 * n + 2];
  __syncthreads();

  // --- phase A: partial max / sumexp2 over this chunk's 128 comps ---
  const float4* __restrict__ pmc = s_pm + ch * 128;
  float ma = -FLT_MAX, mb = -FLT_MAX, mc = -FLT_MAX, md = -FLT_MAX;
#pragma unroll 4
  for (int i = 0; i < 128; i += 4) {
    float4 a = pmc[i], b = pmc[i + 1], c = pmc[i + 2], d = pmc[i + 3];
    ma = fmaxf(ma, fmaf(a.x, x0, fmaf(a.y, x1, fmaf(a.z, x2, a.w))));
    mb = fmaxf(mb, fmaf(b.x, x0, fmaf(b.y, x1, fmaf(b.z, x2, b.w))));
    mc = fmaxf(mc, fmaf(c.x, x0, fmaf(c.y, x1, fmaf(c.z, x2, c.w))));
    md = fmaxf(md, fmaf(d.x, x0, fmaf(d.y, x1, fmaf(d.z, x2, d.w))));
  }
  const float m = fmaxf(fmaxf(ma, mb), fmaxf(mc, md));
  float sa = 0.f, sb = 0.f, sc = 0.f, sd = 0.f;
#pragma unroll 4
  for (int i = 0; i < 128; i += 4) {
    float4 a = pmc[i], b = pmc[i + 1], c = pmc[i + 2], d = pmc[i + 3];
    sa += exp2f(fmaf(a.x, x0, fmaf(a.y, x1, fmaf(a.z, x2, a.w))) - m);
    sb += exp2f(fmaf(b.x, x0, fmaf(b.y, x1, fmaf(b.z, x2, b.w))) - m);
    sc += exp2f(fmaf(c.x, x0, fmaf(c.y, x1, fmaf(c.z, x2, c.w))) - m);
    sd += exp2f(fmaf(d.x, x0, fmaf(d.y, x1, fmaf(d.z, x2, d.w))) - m);
  }
  s_ms[ch][p] = make_float2(m, (sa + sb) + (sc + sd));
  __syncthreads();

  if (t < 128) {  // thread t owns point p == t here
    float2 q0 = s_ms[0][t], q1 = s_ms[1][t], q2 = s_ms[2][t], q3 = s_ms[3][t];
    float M = fmaxf(fmaxf(q0.x, q1.x), fmaxf(q2.x, q3.x));
    float SS = q0.y * exp2f(q0.x - M) + q1.y * exp2f(q1.x - M) +
               q2.y * exp2f(q2.x - M) + q3.y * exp2f(q3.x - M);
    float z2 = M + __log2f(SS);  // base-2 logsumexp
    s_pt[t] = make_float4(x0, x1, x2, z2);
    out[3 * n] = z2;  // staged for k_final (base-2)
  }
  __syncthreads();

  // --- phase C: thread t owns comp t across the block's 128 points ---
  const float4 pc = s_pm[t];  // per-lane conflict-free LDS read
  float Sg = 0.f, Tx = 0.f, Ty = 0.f, Tz = 0.f, La2 = 0.f;
#pragma unroll 4
  for (int i = 0; i < 128; ++i) {
    float4 pt = s_pt[i];  // broadcast read
    float l = fmaf(pc.x, pt.x, fmaf(pc.y, pt.y, fmaf(pc.z, pt.z, pc.w)));
    float d = l - pt.w;   // log2-domain lgamma
    float g = exp2f(d);
    Sg += g;
    Tx = fmaf(g, pt.x, Tx);
    Ty = fmaf(g, pt.y, Ty);
    Tz = fmaf(g, pt.z, Tz);
    La2 = fmaf(g, d, La2);  // sum gamma * lgamma, log2 units
  }
  float* st = ST + (((blockIdx.x & (NREP - 1)) * 512 + t) << 2);
  atomicAdd(st + 0, Tx);
  atomicAdd(st + 1, Ty);
  atomicAdd(st + 2, Tz);
  atomicAdd(st + 3, Sg);

  // --- block reduce: sum|x|^2 (points counted once) and La (natural) ---
  float xx = (t < 128) ? (x0 * x0 + x1 * x1 + x2 * x2) : 0.f;
  float rx = waveSum(xx);
  float rl = waveSum(La2 * LN2);
  if ((t & 63) == 0) { s_red[t >> 6] = rx; s_red2[t >> 6] = rl; }
  __syncthreads();
  if (t == 0) {
    float vx = 0.f, vl = 0.f;
#pragma unroll
    for (int i = 0; i < 8; ++i) { vx += s_red[i]; vl += s_red2[i]; }
    atomicAdd(&misc[0], vx);
    atomicAdd(&misc[3], vl);
  }
}

// ---------------------------------------------------------------------------
// Final: redundant per-block M-step (ST -> pq in LDS, ~2us) + round-0 dense
// Y loop. Block 0 seeds Cfe; all blocks add their per-point -|Y|^2 terms.
// ---------------------------------------------------------------------------
__global__ __launch_bounds__(512, 8) void k_final(
    const float* __restrict__ X, const float* __restrict__ mu,
    const float* __restrict__ w, const float* __restrict__ sigma,
    const float4* __restrict__ ST4, const float* __restrict__ misc,
    float* __restrict__ out) {
  __shared__ float4 s_pm[NC];
  __shared__ float4 s_pq[NC];      // (mu_new[3], A_c)
  __shared__ float4 s_y[4][128];
  __shared__ float  s_red[8];
  __shared__ float  s_red2[8];
  __shared__ float  s_bc[4];

  const int t = threadIdx.x;
  const int p = t & 127;
  const int ch = __builtin_amdgcn_readfirstlane(t >> 7);
  const int n = blockIdx.x * 128 + p;

  s_pm[t] = packComp(mu, w, sigma, t);
  const float x0 = X[3 * n], x1 = X[3 * n + 1], x2 = X[3 * n + 2];
  const float z2 = out[3 * n];  // staged by k_estep (base-2)

  // --- redundant M-step (identical in every block) ---
  float Tx = 0.f, Ty = 0.f, Tz = 0.f, S = 0.f;
#pragma unroll
  for (int r = 0; r < NREP; ++r) {
    float4 v = ST4[r * 512 + t];
    Tx += v.x; Ty += v.y; Tz += v.z; S += v.w;
  }
  const float Sc = fmaxf(S, 1e-30f);
  const float h = __logf(Sc);
  const float m0 = Tx / Sc, m1 = Ty / Sc, m2 = Tz / Sc;

  const float o0 = mu[3 * t], o1 = mu[3 * t + 1], o2 = mu[3 * t + 2];
  const float gdp = S * (o0 * o0 + o1 * o1 + o2 * o2)
                    - 2.0f * (o0 * Tx + o1 * Ty + o2 * Tz);

  float hm = waveMax(h);
  if ((t & 63) == 0) s_red[t >> 6] = hm;
  __syncthreads();
  if (t == 0) {
    float v = s_red[0];
    for (int i = 1; i < 8; ++i) v = fmaxf(v, s_red[i]);
    s_bc[0] = v;
  }
  __syncthreads();
  const float hM = s_bc[0];

  float es = waveSum(__expf(h - hM));
  float gs = waveSum(gdp);
  if ((t & 63) == 0) { s_red[t >> 6] = es; s_red2[t >> 6] = gs; }
  __syncthreads();
  if (t == 0) {
    float esum = 0.f, gsum = 0.f;
    for (int i = 0; i < 8; ++i) { esum += s_red[i]; gsum += s_red2[i]; }
    s_bc[1] = hM + __logf(esum);                           // lse(h)
    const float gd = fmaxf(misc[0] + gsum, 1e-20f);
    const float sn2 = gd * (1.0f / (3.0f * (float)NPTS));  // sigma_new^2
    s_bc[2] = 1.0f / (2.0f * sn2);                         // inv2s2_new
    s_bc[3] = 1.5f * __logf(sn2);                          // d*log(sigma_new)
  }
  __syncthreads();

  const float inv2s2n = s_bc[2];
  const float logpi = h - s_bc[1];
  const float A = (m0 * m0 + m1 * m1 + m2 * m2) * inv2s2n - logpi;
  s_pq[t] = make_float4(m0, m1, m2, A);

  float ca = waveSum(S * A);
  if ((t & 63) == 0) s_red[t >> 6] = ca;
  __syncthreads();  // publishes s_pq + s_red
  if (t == 0 && blockIdx.x == 0) {  // Cfe seed, exactly once
    float v = 0.f;
#pragma unroll
    for (int i = 0; i < 8; ++i) v += s_red[i];
    atomicAdd(&out[(size_t)NPTS * 3], v + misc[3] + (float)NPTS * s_bc[3]);
  }

  // --- dense Y loop (round-0 final_dense, base-2) ---
  const float4* __restrict__ pmc = s_pm + ch * 128;
  const float4* __restrict__ pqc = s_pq + ch * 128;
  float y0 = 0.f, y1 = 0.f, y2 = 0.f;
#pragma unroll 4
  for (int i = 0; i < 128; ++i) {
    float4 pp = pmc[i];
    float4 qq = pqc[i];
    const float l = fmaf(pp.x, x0, fmaf(pp.y, x1, fmaf(pp.z, x2, pp.w))) - z2;
    const float g = exp2f(l);
    y0 = fmaf(g, qq.x, y0);
    y1 = fmaf(g, qq.y, y1);
    y2 = fmaf(g, qq.z, y2);
  }
  s_y[ch][p] = make_float4(y0, y1, y2, 0.f);
  __syncthreads();

  float cfe = 0.f;
  if (t < 128) {  // p == t here
    float4 a0 = s_y[0][t], a1 = s_y[1][t], a2 = s_y[2][t], a3 = s_y[3][t];
    const float Y0 = (a0.x + a1.x) + (a2.x + a3.x);
    const float Y1 = (a0.y + a1.y) + (a2.y + a3.y);
    const float Y2 = (a0.z + a1.z) + (a2.z + a3.z);
    cfe = -(Y0 * Y0 + Y1 * Y1 + Y2 * Y2) * inv2s2n;
    out[3 * n] = Y0;
    out[3 * n + 1] = Y1;
    out[3 * n + 2] = Y2;
  }
  float r = waveSum(cfe);
  if ((t & 63) == 0) s_red[t >> 6] = r;
  __syncthreads();
  if (t == 0) {
    float v = 0.f;
#pragma unroll
    for (int i = 0; i < 8; ++i) v += s_red[i];
    atomicAdd(&out[(size_t)NPTS * 3], v);
  }
}

extern "C" void kernel_launch(void* const* d_in, const int* in_sizes, int n_in,
                              void* d_out, int out_size, void* d_ws, size_t ws_size,
                              hipStream_t stream) {
  const float* X = (const float*)d_in[0];
  const float* mu = (const float*)d_in[1];
  const float* w = (const float*)d_in[2];
  const float* sigma = (const float*)d_in[3];
  float* out = (float*)d_out;
  float* ws = (float*)d_ws;

  float* ST = ws + ST4_OFF;
  float* misc = ws + MISC_OFF;

  // 3 dispatches total: zero accumulators, E-step, M-step+final (fused).
  hipMemsetAsync(ST, 0, (size_t)(NREP * NC * 4 + 8) * sizeof(float), stream);
  k_estep<<<NT, 512, 0, stream>>>(X, mu, w, sigma, ST, misc, out);
  k_final<<<NT, 512, 0, stream>>>(X, mu, w, sigma, (const float4*)ST, misc, out);
}

// Round 8
// 147.443 us; speedup vs baseline: 2.2434x; 1.0253x over previous
//
#include <hip/hip_runtime.h>
#include <cfloat>
#include <cmath>

#define NPTS 131072
#define NC   512
#define NREP 4
#define NT   (NPTS / 128)

// ws float-index layout (pm/pq live in LDS only):
//  ST4  [4096, 12288)  : NREP replicas x 512 comps x float4 (Tx,Ty,Tz,S)
//  MISC [12288, 12296) : [0]=sum|x|^2, [3]=sum(gamma*lgamma)
// z_n (natural log) staged in d_out[3n]; Cfe accumulates in d_out[NPTS*3]
// (zeroed by k_estep block 0 -- stream order guarantees it precedes k_final).
#define ST4_OFF  4096
#define MISC_OFF 12288

__device__ __forceinline__ float waveSum(float v) {
#pragma unroll
  for (int off = 32; off > 0; off >>= 1) v += __shfl_down(v, off, 64);
  return v;
}
__device__ __forceinline__ float waveMax(float v) {
#pragma unroll
  for (int off = 32; off > 0; off >>= 1) v = fmaxf(v, __shfl_down(v, off, 64));
  return v;
}

// Packed component params, NATURAL-log domain (round-0 k_prep exactly):
// l = dot(pm.xyz, x) + pm.w = w_c - |x-mu_c|^2/(2s^2) + |x|^2/(2s^2)-shift.
// All exps via __expf (single v_mul+v_exp); exp2f/log2f are PRECISE OCML
// multi-instruction calls without -ffast-math (round-7 lesson: +19% VALU).
__device__ __forceinline__ float4 packComp(
    const float* __restrict__ mu, const float* __restrict__ w,
    const float* __restrict__ sigma, int t) {
  const float sg = sigma[0];
  const float inv2s2 = 1.0f / (2.0f * sg * sg);
  const float m0 = mu[3 * t], m1 = mu[3 * t + 1], m2 = mu[3 * t + 2];
  return make_float4(2.0f * inv2s2 * m0, 2.0f * inv2s2 * m1,
                     2.0f * inv2s2 * m2,
                     w[t] - (m0 * m0 + m1 * m1 + m2 * m2) * inv2s2);
}

// ---------------------------------------------------------------------------
// E-step (round-0 structure + codegen; pm staged in LDS by packComp).
// block = 512 thr = 128 points x 4 comp-chunks.
// Phase A: per-chunk (max, sumexp) -> combine -> z. Phase C: thread owns
// one comp over 128 points (LDS broadcast); ST replica atomics.
// ---------------------------------------------------------------------------
__global__ __launch_bounds__(512, 8) void k_estep(
    const float* __restrict__ X, const float* __restrict__ mu,
    const float* __restrict__ w, const float* __restrict__ sigma,
    float* __restrict__ ST, float* __restrict__ misc,
    float* __restrict__ out) {
  __shared__ float4 s_pm[NC];      // packed comp params (natural log)
  __shared__ float4 s_pt[128];     // (x0,x1,x2,z)
  __shared__ float2 s_ms[4][128];  // per-chunk (max, sumexp)
  __shared__ float  s_red[8];
  __shared__ float  s_red2[8];

  const int t = threadIdx.x;
  const int p = t & 127;
  const int ch = __builtin_amdgcn_readfirstlane(t >> 7);  // wave-uniform
  const int n = blockIdx.x * 128 + p;

  s_pm[t] = packComp(mu, w, sigma, t);
  if (blockIdx.x == 0 && t == 0) out[(size_t)NPTS * 3] = 0.f;  // Cfe slot
  const float x0 = X[3 * n], x1 = X[3 * n + 1], x2 = X[3 * n + 2];
  __syncthreads();

  // --- phase A: partial max / sumexp over this chunk's 128 comps ---
  const float4* __restrict__ pmc = s_pm + ch * 128;
  float ma = -FLT_MAX, mb = -FLT_MAX, mc = -FLT_MAX, md = -FLT_MAX;
#pragma unroll 4
  for (int i = 0; i < 128; i += 4) {
    float4 a = pmc[i], b = pmc[i + 1], c = pmc[i + 2], d = pmc[i + 3];
    ma = fmaxf(ma, fmaf(a.x, x0, fmaf(a.y, x1, fmaf(a.z, x2, a.w))));
    mb = fmaxf(mb, fmaf(b.x, x0, fmaf(b.y, x1, fmaf(b.z, x2, b.w))));
    mc = fmaxf(mc, fmaf(c.x, x0, fmaf(c.y, x1, fmaf(c.z, x2, c.w))));
    md = fmaxf(md, fmaf(d.x, x0, fmaf(d.y, x1, fmaf(d.z, x2, d.w))));
  }
  const float m = fmaxf(fmaxf(ma, mb), fmaxf(mc, md));
  float sa = 0.f, sb = 0.f, sc = 0.f, sd = 0.f;
#pragma unroll 4
  for (int i = 0; i < 128; i += 4) {
    float4 a = pmc[i], b = pmc[i + 1], c = pmc[i + 2], d = pmc[i + 3];
    sa += __expf(fmaf(a.x, x0, fmaf(a.y, x1, fmaf(a.z, x2, a.w))) - m);
    sb += __expf(fmaf(b.x, x0, fmaf(b.y, x1, fmaf(b.z, x2, b.w))) - m);
    sc += __expf(fmaf(c.x, x0, fmaf(c.y, x1, fmaf(c.z, x2, c.w))) - m);
    sd += __expf(fmaf(d.x, x0, fmaf(d.y, x1, fmaf(d.z, x2, d.w))) - m);
  }
  s_ms[ch][p] = make_float2(m, (sa + sb) + (sc + sd));
  __syncthreads();

  if (t < 128) {  // thread t owns point p == t here
    float2 q0 = s_ms[0][t], q1 = s_ms[1][t], q2 = s_ms[2][t], q3 = s_ms[3][t];
    float M = fmaxf(fmaxf(q0.x, q1.x), fmaxf(q2.x, q3.x));
    float SS = q0.y * __expf(q0.x - M) + q1.y * __expf(q1.x - M) +
               q2.y * __expf(q2.x - M) + q3.y * __expf(q3.x - M);
    float z = M + __logf(SS);
    s_pt[t] = make_float4(x0, x1, x2, z);
    out[3 * n] = z;  // staged for k_final (natural log)
  }
  __syncthreads();

  // --- phase C: thread t owns comp t across the block's 128 points ---
  const float4 pc = s_pm[t];  // per-lane conflict-free LDS read
  float Sg = 0.f, Tx = 0.f, Ty = 0.f, Tz = 0.f, La = 0.f;
#pragma unroll 4
  for (int i = 0; i < 128; ++i) {
    float4 pt = s_pt[i];  // broadcast read
    float l = fmaf(pc.x, pt.x, fmaf(pc.y, pt.y, fmaf(pc.z, pt.z, pc.w)));
    float d = l - pt.w;   // lgamma
    float g = __expf(d);
    Sg += g;
    Tx = fmaf(g, pt.x, Tx);
    Ty = fmaf(g, pt.y, Ty);
    Tz = fmaf(g, pt.z, Tz);
    La = fmaf(g, d, La);  // sum gamma * lgamma
  }
  float* st = ST + (((blockIdx.x & (NREP - 1)) * 512 + t) << 2);
  atomicAdd(st + 0, Tx);
  atomicAdd(st + 1, Ty);
  atomicAdd(st + 2, Tz);
  atomicAdd(st + 3, Sg);

  // --- block reduce: sum|x|^2 (points counted once) and La ---
  float xx = (t < 128) ? (x0 * x0 + x1 * x1 + x2 * x2) : 0.f;
  float rx = waveSum(xx);
  float rl = waveSum(La);
  if ((t & 63) == 0) { s_red[t >> 6] = rx; s_red2[t >> 6] = rl; }
  __syncthreads();
  if (t == 0) {
    float vx = 0.f, vl = 0.f;
#pragma unroll
    for (int i = 0; i < 8; ++i) { vx += s_red[i]; vl += s_red2[i]; }
    atomicAdd(&misc[0], vx);
    atomicAdd(&misc[3], vl);
  }
}

// ---------------------------------------------------------------------------
// Final: redundant per-block M-step (ST -> pq in LDS) + round-0 dense Y loop.
// Block 0 seeds Cfe; all blocks add their per-point -|Y|^2 terms.
// ---------------------------------------------------------------------------
__global__ __launch_bounds__(512, 8) void k_final(
    const float* __restrict__ X, const float* __restrict__ mu,
    const float* __restrict__ w, const float* __restrict__ sigma,
    const float4* __restrict__ ST4, const float* __restrict__ misc,
    float* __restrict__ out) {
  __shared__ float4 s_pm[NC];
  __shared__ float4 s_pq[NC];      // (mu_new[3], A_c)
  __shared__ float4 s_y[4][128];
  __shared__ float  s_red[8];
  __shared__ float  s_red2[8];
  __shared__ float  s_bc[4];

  const int t = threadIdx.x;
  const int p = t & 127;
  const int ch = __builtin_amdgcn_readfirstlane(t >> 7);
  const int n = blockIdx.x * 128 + p;

  s_pm[t] = packComp(mu, w, sigma, t);
  const float x0 = X[3 * n], x1 = X[3 * n + 1], x2 = X[3 * n + 2];
  const float z = out[3 * n];  // staged by k_estep (natural log)

  // --- redundant M-step (identical in every block) ---
  float Tx = 0.f, Ty = 0.f, Tz = 0.f, S = 0.f;
#pragma unroll
  for (int r = 0; r < NREP; ++r) {
    float4 v = ST4[r * 512 + t];
    Tx += v.x; Ty += v.y; Tz += v.z; S += v.w;
  }
  const float Sc = fmaxf(S, 1e-30f);
  const float h = __logf(Sc);
  const float m0 = Tx / Sc, m1 = Ty / Sc, m2 = Tz / Sc;

  const float o0 = mu[3 * t], o1 = mu[3 * t + 1], o2 = mu[3 * t + 2];
  const float gdp = S * (o0 * o0 + o1 * o1 + o2 * o2)
                    - 2.0f * (o0 * Tx + o1 * Ty + o2 * Tz);

  float hm = waveMax(h);
  if ((t & 63) == 0) s_red[t >> 6] = hm;
  __syncthreads();
  if (t == 0) {
    float v = s_red[0];
    for (int i = 1; i < 8; ++i) v = fmaxf(v, s_red[i]);
    s_bc[0] = v;
  }
  __syncthreads();
  const float hM = s_bc[0];

  float es = waveSum(__expf(h - hM));
  float gs = waveSum(gdp);
  if ((t & 63) == 0) { s_red[t >> 6] = es; s_red2[t >> 6] = gs; }
  __syncthreads();
  if (t == 0) {
    float esum = 0.f, gsum = 0.f;
    for (int i = 0; i < 8; ++i) { esum += s_red[i]; gsum += s_red2[i]; }
    s_bc[1] = hM + __logf(esum);                           // lse(h)
    const float gd = fmaxf(misc[0] + gsum, 1e-20f);
    const float sn2 = gd * (1.0f / (3.0f * (float)NPTS));  // sigma_new^2
    s_bc[2] = 1.0f / (2.0f * sn2);                         // inv2s2_new
    s_bc[3] = 1.5f * __logf(sn2);                          // d*log(sigma_new)
  }
  __syncthreads();

  const float inv2s2n = s_bc[2];
  const float logpi = h - s_bc[1];
  const float A = (m0 * m0 + m1 * m1 + m2 * m2) * inv2s2n - logpi;
  s_pq[t] = make_float4(m0, m1, m2, A);

  float ca = waveSum(S * A);
  if ((t & 63) == 0) s_red[t >> 6] = ca;
  __syncthreads();  // publishes s_pq + s_red
  if (t == 0 && blockIdx.x == 0) {  // Cfe seed, exactly once
    float v = 0.f;
#pragma unroll
    for (int i = 0; i < 8; ++i) v += s_red[i];
    atomicAdd(&out[(size_t)NPTS * 3], v + misc[3] + (float)NPTS * s_bc[3]);
  }

  // --- dense Y loop (round-0 final_dense) ---
  const float4* __restrict__ pmc = s_pm + ch * 128;
  const float4* __restrict__ pqc = s_pq + ch * 128;
  float y0 = 0.f, y1 = 0.f, y2 = 0.f;
#pragma unroll 4
  for (int i = 0; i < 128; ++i) {
    float4 pp = pmc[i];
    float4 qq = pqc[i];
    const float l = fmaf(pp.x, x0, fmaf(pp.y, x1, fmaf(pp.z, x2, pp.w))) - z;
    const float g = __expf(l);
    y0 = fmaf(g, qq.x, y0);
    y1 = fmaf(g, qq.y, y1);
    y2 = fmaf(g, qq.z, y2);
  }
  s_y[ch][p] = make_float4(y0, y1, y2, 0.f);
  __syncthreads();

  float cfe = 0.f;
  if (t < 128) {  // p == t here
    float4 a0 = s_y[0][t], a1 = s_y[1][t], a2 = s_y[2][t], a3 = s_y[3][t];
    const float Y0 = (a0.x + a1.x) + (a2.x + a3.x);
    const float Y1 = (a0.y + a1.y) + (a2.y + a3.y);
    const float Y2 = (a0.z + a1.z) + (a2.z + a3.z);
    cfe = -(Y0 * Y0 + Y1 * Y1 + Y2 * Y2) * inv2s2n;
    out[3 * n] = Y0;
    out[3 * n + 1] = Y1;
    out[3 * n + 2] = Y2;
  }
  float r = waveSum(cfe);
  if ((t & 63) == 0) s_red[t >> 6] = r;
  __syncthreads();
  if (t == 0) {
    float v = 0.f;
#pragma unroll
    for (int i = 0; i < 8; ++i) v += s_red[i];
    atomicAdd(&out[(size_t)NPTS * 3], v);
  }
}

extern "C" void kernel_launch(void* const* d_in, const int* in_sizes, int n_in,
                              void* d_out, int out_size, void* d_ws, size_t ws_size,
                              hipStream_t stream) {
  const float* X = (const float*)d_in[0];
  const float* mu = (const float*)d_in[1];
  const float* w = (const float*)d_in[2];
  const float* sigma = (const float*)d_in[3];
  float* out = (float*)d_out;
  float* ws = (float*)d_ws;

  float* ST = ws + ST4_OFF;
  float* misc = ws + MISC_OFF;

  // 3 dispatches total: zero accumulators, E-step, M-step+final (fused).
  hipMemsetAsync(ST, 0, (size_t)(NREP * NC * 4 + 8) * sizeof(float), stream);
  k_estep<<<NT, 512, 0, stream>>>(X, mu, w, sigma, ST, misc, out);
  k_final<<<NT, 512, 0, stream>>>(X, mu, w, sigma, (const float4*)ST, misc, out);
}